// Round 10
// baseline (436.576 us; speedup 1.0000x reference)
//
#include <hip/hip_runtime.h>
#include <hip/hip_bf16.h>
#include <math.h>

// AKOrN layer: B=2, N=1024, D=256, H=4 (dk=64), O=8, DT=0.1, STEPS=5
// TWO plain launches (no cooperative API — R6 lesson):
//   k_projm : dtype-detect + bf16 cvt; MFMA GEMM -> Qb(x0.125), Kb,
//             PH0 fp32 [bh][o][n], SC0 bf16 sin/cos; zeroes barrier counters.
//   k_mega2 : per block (bh, 16 rows): scores+exp -> U in LDS ONLY (block-
//             private!), rowsum -> Rsh; then 5 Kuramoto steps with a manual
//             device-scope grid barrier between (bounded spin — cannot hang);
//             phases live in wave-0 registers; SC ping-pongs in global
//             (256 KB); finally the out-projection (cos @ Wo.T + bo) fused
//             after the last barrier.
//
// Workspace: Qb @0 (1M) | Kb @1M (1M) | PH0 @2M (256K) | SC0 @2M+256K (256K)
//            SCA @2M+512K (256K) | ctr @3M (32B)

#define NB 1024
#define NH 4
#define DD 256
#define NO 8
#define PI_F      3.14159265358979323846f
#define TWO_PI_F  6.28318530717958647692f
#define INV_2PI_F 0.15915494309189533577f

typedef __attribute__((ext_vector_type(8))) short bf16x8;
typedef __attribute__((ext_vector_type(4))) float f32x4;

__device__ __forceinline__ float b2f_u(unsigned short s) {
    union { unsigned u; float f; } x; x.u = ((unsigned)s) << 16; return x.f;
}
__device__ __forceinline__ unsigned short f2b(float f) {
    union { float f; unsigned u; } v; v.f = f;
    unsigned r = v.u + 0x7FFFu + ((v.u >> 16) & 1u);   // RTNE
    return (unsigned short)(r >> 16);
}
template<bool F32>
__device__ __forceinline__ uint4 load_pack8(const void* p, size_t off) {
    if (!F32) return *(const uint4*)((const unsigned short*)p + off);
    const float* fp = (const float*)p + off;
    float4 a = *(const float4*)fp;
    float4 b = *(const float4*)(fp + 4);
    uint4 r;
    r.x = (unsigned)f2b(a.x) | ((unsigned)f2b(a.y) << 16);
    r.y = (unsigned)f2b(a.z) | ((unsigned)f2b(a.w) << 16);
    r.z = (unsigned)f2b(b.x) | ((unsigned)f2b(b.y) << 16);
    r.w = (unsigned)f2b(b.z) | ((unsigned)f2b(b.w) << 16);
    return r;
}
__device__ __forceinline__ void load8_rt(int f32, const void* p, int i, float* f) {
    if (f32) {
        const float* fp = (const float*)p + i;
        float4 a = *(const float4*)fp;
        float4 b = *(const float4*)(fp + 4);
        f[0]=a.x; f[1]=a.y; f[2]=a.z; f[3]=a.w;
        f[4]=b.x; f[5]=b.y; f[6]=b.z; f[7]=b.w;
    } else {
        uint4 u = *(const uint4*)((const unsigned short*)p + i);
        f[0] = b2f_u(u.x & 0xFFFFu); f[1] = b2f_u(u.x >> 16);
        f[2] = b2f_u(u.y & 0xFFFFu); f[3] = b2f_u(u.y >> 16);
        f[4] = b2f_u(u.z & 0xFFFFu); f[5] = b2f_u(u.z >> 16);
        f[6] = b2f_u(u.w & 0xFFFFu); f[7] = b2f_u(u.w >> 16);
    }
}
__device__ __forceinline__ float read_cs_bf16(const void* p) {
    float vb = b2f_u(*(const unsigned short*)p);
    bool ok = isfinite(vb) && fabsf(vb) > 1e-30f && fabsf(vb) < 1e30f;
    if (ok) return vb;
    return *(const float*)p;
}
__device__ __forceinline__ int detect_inline(const unsigned short* x) {
    int l = threadIdx.x & 63;
    float a0 = fabsf(b2f_u(x[2 * l]));
    float a1 = fabsf(b2f_u(x[2 * (l + 64)]));
    unsigned long long b0 = __ballot(!(a0 >= 1e-10f && a0 <= 100.0f));
    unsigned long long b1 = __ballot(!(a1 >= 1e-10f && a1 <= 100.0f));
    return (__popcll(b0) + __popcll(b1)) > 16;
}

// ---------------------------------------------------------------------------
// K1: MFMA projection GEMM with inline conversion. Grid 288 = 32 i x 9 f.
// ftile 0-3 -> Qb(x0.125), 4-7 -> Kb, 8 -> PH0(+bp) + SC0.
// Block 0 zeroes the mega-kernel's barrier counters.
// ---------------------------------------------------------------------------
template<bool F32>
__device__ void projm_impl(
    const void* __restrict__ x, const void* __restrict__ Wq,
    const void* __restrict__ Wk, const void* __restrict__ Wp,
    const void* __restrict__ bp,
    unsigned short* __restrict__ Qb, unsigned short* __restrict__ Kb,
    float* __restrict__ PH, unsigned short* __restrict__ SC)
{
    __shared__ uint4 Xsh[64 * 32];   // 32 KB
    __shared__ uint4 Wsh[64 * 32];   // 32 KB
    const int tid = threadIdx.x;
    const int ftile = blockIdx.x % 9, itile = blockIdx.x / 9;
    const int i0 = itile * 64, f0 = ftile * 64;
    const int wave = tid >> 6, lane = tid & 63;
    const int n = lane & 15, quad = lane >> 4;

    #pragma unroll
    for (int g = 0; g < 8; g++) {
        int fidx = g * 256 + tid;
        int row = fidx >> 5, q = fidx & 31;
        int sw = (q & 24) | ((q ^ row) & 7);
        Xsh[row * 32 + sw] = load_pack8<F32>(x, (size_t)(i0 + row) * 256 + q * 8);
        int wr = f0 + row;
        uint4 wv = make_uint4(0, 0, 0, 0);
        if (wr < 256)      wv = load_pack8<F32>(Wq, (size_t)wr * 256 + q * 8);
        else if (wr < 512) wv = load_pack8<F32>(Wk, (size_t)(wr - 256) * 256 + q * 8);
        else if (wr < 544) wv = load_pack8<F32>(Wp, (size_t)(wr - 512) * 256 + q * 8);
        Wsh[row * 32 + sw] = wv;
    }
    __syncthreads();

    f32x4 acc[4];
    #pragma unroll
    for (int s = 0; s < 4; s++) acc[s] = (f32x4){0.f, 0.f, 0.f, 0.f};
    const int xrow = wave * 16 + n;
    #pragma unroll
    for (int s = 0; s < 8; s++) {
        int qc = s * 4 + quad;
        bf16x8 b = ((const bf16x8*)Xsh)[xrow * 32 + ((qc & 24) | ((qc ^ xrow) & 7))];
        #pragma unroll
        for (int sub = 0; sub < 4; sub++) {
            int wr = sub * 16 + n;
            bf16x8 a = ((const bf16x8*)Wsh)[wr * 32 + ((qc & 24) | ((qc ^ wr) & 7))];
            acc[sub] = __builtin_amdgcn_mfma_f32_16x16x32_bf16(a, b, acc[sub], 0, 0, 0);
        }
    }

    const int ig = i0 + wave * 16 + n;
    const int bb = ig >> 10, nr = ig & 1023;
    if (ftile < 4) {
        #pragma unroll
        for (int sub = 0; sub < 4; sub++) {
            int dd = sub * 16 + quad * 4;
            ushort4 v = make_ushort4(f2b(acc[sub][0] * 0.125f), f2b(acc[sub][1] * 0.125f),
                                     f2b(acc[sub][2] * 0.125f), f2b(acc[sub][3] * 0.125f));
            *(ushort4*)(Qb + ((size_t)((bb * NH + ftile) * NB + nr)) * 64 + dd) = v;
        }
    } else if (ftile < 8) {
        int h = ftile - 4;
        #pragma unroll
        for (int sub = 0; sub < 4; sub++) {
            int dd = sub * 16 + quad * 4;
            ushort4 v = make_ushort4(f2b(acc[sub][0]), f2b(acc[sub][1]),
                                     f2b(acc[sub][2]), f2b(acc[sub][3]));
            *(ushort4*)(Kb + ((size_t)((bb * NH + h) * NB + nr)) * 64 + dd) = v;
        }
    } else {
        #pragma unroll
        for (int sub = 0; sub < 2; sub++) {
            #pragma unroll
            for (int r = 0; r < 4; r++) {
                int fp = sub * 16 + quad * 4 + r;       // 0..31
                int h2 = fp >> 3, o = fp & 7;
                float bpv = F32 ? ((const float*)bp)[fp]
                                : b2f_u(((const unsigned short*)bp)[fp]);
                float v = acc[sub][r] + bpv;
                int bh = bb * NH + h2;
                PH[(size_t)bh * 8192 + o * 1024 + nr] = v;
                float sv, cv;
                __sincosf(v, &sv, &cv);
                SC[(size_t)(bh * 16 + o) * 1024 + nr]     = f2b(sv);
                SC[(size_t)(bh * 16 + 8 + o) * 1024 + nr] = f2b(cv);
            }
        }
    }
}

__global__ __launch_bounds__(256) void k_projm(
    const unsigned short* x, const void* Wq, const void* Wk, const void* Wp,
    const void* bp, unsigned short* Qb, unsigned short* Kb, float* PH,
    unsigned short* SC, unsigned int* ctr)
{
    if (blockIdx.x == 0 && threadIdx.x < 8) ctr[threadIdx.x] = 0u;
    if (detect_inline(x)) projm_impl<true >(x, Wq, Wk, Wp, bp, Qb, Kb, PH, SC);
    else                  projm_impl<false>(x, Wq, Wk, Wp, bp, Qb, Kb, PH, SC);
}

// ---------------------------------------------------------------------------
// K2: mega kernel. Grid 512 = 8 bh x 64 chunks of 16 rows; 256 thr; ~37 KB
// LDS -> 2 blocks/CU -> all 512 co-resident (manual barrier is safe; spin is
// BOUNDED so a residency failure gives wrong results, never a hang).
// ---------------------------------------------------------------------------
__global__ __launch_bounds__(256) void k_mega2(
    const unsigned short* __restrict__ xraw,
    const unsigned short* __restrict__ Qb, const unsigned short* __restrict__ Kb,
    const float* __restrict__ PH0,
    unsigned short* __restrict__ SC0, unsigned short* __restrict__ SCA,
    const void* __restrict__ omega, const void* __restrict__ csp,
    const void* __restrict__ Wo, const void* __restrict__ bo,
    void* __restrict__ out, unsigned int* __restrict__ ctr)
{
    __shared__ uint4 Ush[16 * 128];   // 32 KB block-private U tile
    __shared__ f32x4 red[4][64];      // 4 KB
    __shared__ float redS[4][16];
    __shared__ float Rsh[16];
    __shared__ float sig[4][32];

    const int tid = threadIdx.x;
    const int bid = blockIdx.x;
    const int bh  = bid >> 6;
    const int i0  = (bid & 63) * 16;
    const int wave = tid >> 6, lane = tid & 63;
    const int n = lane & 15, quad = lane >> 4;
    const int f32 = detect_inline(xraw);

    // ---- phase A: scores + exp -> Ush (LDS only!), rowsum -> Rsh ----
    const unsigned short* qrow = Qb + ((size_t)(bh * NB) + i0 + n) * 64;
    bf16x8 bq0 = *(const bf16x8*)(qrow + quad * 8);
    bf16x8 bq1 = *(const bf16x8*)(qrow + 32 + quad * 8);
    float s = 0.f;
    const unsigned short* kbase = Kb + ((size_t)(bh * NB) + n) * 64;
    #pragma unroll
    for (int t = 0; t < 16; t++) {
        int jt = wave * 16 + t;                       // j-tile 0..63
        const unsigned short* arow = kbase + (size_t)jt * 16 * 64;
        bf16x8 a0 = *(const bf16x8*)(arow + quad * 8);
        bf16x8 a1 = *(const bf16x8*)(arow + 32 + quad * 8);
        f32x4 acc = {0.f, 0.f, 0.f, 0.f};
        acc = __builtin_amdgcn_mfma_f32_16x16x32_bf16(a0, bq0, acc, 0, 0, 0);
        acc = __builtin_amdgcn_mfma_f32_16x16x32_bf16(a1, bq1, acc, 0, 0, 0);
        float u0 = __expf(acc[0]);
        float u1 = __expf(acc[1]);
        float u2 = __expf(acc[2]);
        float u3 = __expf(acc[3]);
        s += (u0 + u1) + (u2 + u3);
        ushort4 uv = make_ushort4(f2b(u0), f2b(u1), f2b(u2), f2b(u3));
        int cw = 2 * jt + (quad >> 1);
        ((ushort4*)Ush)[(n * 128 + (cw ^ (n & 7))) * 2 + (quad & 1)] = uv;
    }
    s += __shfl_xor(s, 16);
    s += __shfl_xor(s, 32);
    if (lane < 16) redS[wave][lane] = s;
    __syncthreads();
    if (tid < 16)
        Rsh[tid] = 1.0f / (redS[0][tid] + redS[1][tid] + redS[2][tid] + redS[3][tid]);

    // ---- wave-0 persistent oscillator state (phases in registers) ----
    float P[4];
    float cs_ = 0.f, om_ = 0.f;
    if (wave == 0 && n < 8) {
        const int o = n, h = bh & 3;
        cs_ = f32 ? *(const float*)csp : read_cs_bf16(csp);
        om_ = f32 ? ((const float*)omega)[h * NO + o]
                  : b2f_u(((const unsigned short*)omega)[h * NO + o]);
        float4 pv = *(const float4*)(PH0 + (size_t)bh * 8192 + o * 1024 + i0 + quad * 4);
        P[0] = pv.x; P[1] = pv.y; P[2] = pv.z; P[3] = pv.w;
    }

    unsigned short* scin  = SC0;
    unsigned short* scout = SCA;

    // ---- 5 Kuramoto steps with manual (bounded) grid barriers ----
    #pragma unroll 1
    for (int k = 0; k < 5; k++) {
        const unsigned short* scrow = scin + (size_t)(bh * 16 + n) * 1024;
        f32x4 acc = {0.f, 0.f, 0.f, 0.f};
        #pragma unroll
        for (int t = 0; t < 8; t++) {
            int it = wave * 8 + t;
            bf16x8 a = ((const bf16x8*)Ush)[n * 128 + ((it * 4 + quad) ^ (n & 7))];
            bf16x8 b = *(const bf16x8*)(scrow + it * 32 + quad * 8);
            acc = __builtin_amdgcn_mfma_f32_16x16x32_bf16(a, b, acc, 0, 0, 0);
        }
        red[wave][lane] = acc;
        __syncthreads();

        if (wave == 0) {
            f32x4 a0 = red[0][lane], a1 = red[1][lane];
            f32x4 a2 = red[2][lane], a3 = red[3][lane];
            #pragma unroll
            for (int v = 0; v < 4; v++) acc[v] = (a0[v] + a1[v]) + (a2[v] + a3[v]);
            float C0 = __shfl_xor(acc[0], 8);
            float C1 = __shfl_xor(acc[1], 8);
            float C2 = __shfl_xor(acc[2], 8);
            float C3 = __shfl_xor(acc[3], 8);
            if (n < 8) {
                const int o = n;
                float S[4] = {acc[0], acc[1], acc[2], acc[3]};
                float C[4] = {C0, C1, C2, C3};
                float Rr[4] = {Rsh[quad * 4], Rsh[quad * 4 + 1],
                               Rsh[quad * 4 + 2], Rsh[quad * 4 + 3]};
                #pragma unroll
                for (int r = 0; r < 4; r++) {
                    float si, ci;
                    __sincosf(P[r], &si, &ci);
                    float coup = (ci * S[r] - si * C[r]) * Rr[r];
                    float v = P[r] + 0.1f * (om_ + cs_ * coup);
                    float t2 = v + PI_F;
                    t2 -= floorf(t2 * INV_2PI_F) * TWO_PI_F;   // jnp.remainder
                    P[r] = t2 - PI_F;
                    float sn, cn;
                    __sincosf(P[r], &sn, &cn);
                    int i = i0 + quad * 4 + r;
                    scout[(size_t)(bh * 16 + o) * 1024 + i]     = f2b(sn);
                    scout[(size_t)(bh * 16 + 8 + o) * 1024 + i] = f2b(cn);
                }
            }
        }
        __syncthreads();   // drains wave-0's SC stores (vmcnt0 before s_barrier)
        if (tid == 0) {
            __threadfence();                       // release: wb L2
            atomicAdd(&ctr[k], 1u);
            unsigned spins = 0;
            while (__hip_atomic_load(&ctr[k], __ATOMIC_RELAXED,
                                     __HIP_MEMORY_SCOPE_AGENT) < 512u) {
                __builtin_amdgcn_s_sleep(8);
                if (++spins > (1u << 20)) break;   // bounded: cannot hang
            }
        }
        __syncthreads();
        __threadfence();                           // acquire: invalidate caches
        unsigned short* tmp = scin; scin = scout; scout = tmp;
    }

    // ---- fused output projection: bid -> (b, 4 n-rows) ----
    const int ob = bid >> 8, n0 = (bid & 255) * 4;
    if (tid < 128) {
        int r = tid >> 5, f = tid & 31;
        int h = f >> 3, o = f & 7;
        sig[r][f] = b2f_u(scin[(size_t)((ob * NH + h) * 16 + 8 + o) * 1024 + n0 + r]);
    }
    __syncthreads();
    float wv[32];
    #pragma unroll
    for (int d0 = 0; d0 < 32; d0 += 8) load8_rt(f32, Wo, tid * 32 + d0, wv + d0);
    const float bov = f32 ? ((const float*)bo)[tid] : b2f_u(((const unsigned short*)bo)[tid]);
    #pragma unroll
    for (int r = 0; r < 4; r++) {
        float acc = bov;
        #pragma unroll
        for (int t = 0; t < 32; t++) acc += sig[r][t] * wv[t];
        size_t oi = ((size_t)ob * 1024 + n0 + r) * DD + tid;
        if (f32) ((float*)out)[oi] = acc;
        else     ((unsigned short*)out)[oi] = f2b(acc);
    }
}

// ---------------------------------------------------------------------------
extern "C" void kernel_launch(void* const* d_in, const int* in_sizes, int n_in,
                              void* d_out, int out_size, void* d_ws, size_t ws_size,
                              hipStream_t stream)
{
    const unsigned short* x = (const unsigned short*)d_in[0];
    const void* Wq  = d_in[1];
    const void* Wk  = d_in[2];
    const void* Wp  = d_in[3];
    const void* bp  = d_in[4];
    const void* Wo  = d_in[5];
    const void* bo  = d_in[6];
    const void* om  = d_in[7];
    const void* cs  = d_in[8];

    char* w = (char*)d_ws;
    unsigned short* Qb  = (unsigned short*)w;
    unsigned short* Kb  = (unsigned short*)(w + (1u << 20));
    float*          PH0 = (float*)(w + (2u << 20));
    unsigned short* SC0 = (unsigned short*)(w + (2u << 20) + (256u << 10));
    unsigned short* SCA = (unsigned short*)(w + (2u << 20) + (512u << 10));
    unsigned int*   ctr = (unsigned int*)(w + (3u << 20));

    k_projm<<<288, 256, 0, stream>>>(x, Wq, Wk, Wp, bp, Qb, Kb, PH0, SC0, ctr);
    k_mega2<<<512, 256, 0, stream>>>(x, Qb, Kb, PH0, SC0, SCA, om, cs,
                                     Wo, bo, d_out, ctr);
}

// Round 11
// 169.281 us; speedup vs baseline: 2.5790x; 2.5790x over previous
//
#include <hip/hip_runtime.h>
#include <hip/hip_bf16.h>
#include <math.h>

// AKOrN layer: B=2, N=1024, D=256, H=4 (dk=64), O=8, DT=0.1, STEPS=5
// TWO plain launches. R10 lesson: __threadfence() = buffer_wbl2/inv (full L2
// writeback/invalidate) made the grid barrier cost ~70us each. R11: NO fences
// anywhere — cross-block SC exchange uses relaxed AGENT-scope 8B atomics
// (sc0 sc1: bypass L1/L2, coherent at LLC); store->signal ordering comes from
// __syncthreads' vmcnt(0) drain before the device-scope atomicAdd; barriers
// are per-bh (64 participants, private cache line), spin is BOUNDED.
//
//   k_projm : dtype-detect + bf16 cvt; MFMA GEMM -> Qb(x0.125), Kb,
//             PH0 fp32 [bh][o][n], SC0 bf16 sin/cos; zeroes barrier counters.
//   k_mega3 : scores+exp -> U in LDS (block-private), rowsum -> Rsh;
//             5 Kuramoto steps, phases in wave-0 registers, SC ping-pong via
//             LLC-coherent atomics, per-bh barrier between steps;
//             fused output projection at the end.
//
// Workspace: Qb @0 (1M) | Kb @1M (1M) | PH0 @2M (256K) | SC0 @2M+256K (256K)
//            SCA @2M+512K (256K) | ctr @3M (5120B)

#define NB 1024
#define NH 4
#define DD 256
#define NO 8
#define PI_F      3.14159265358979323846f
#define TWO_PI_F  6.28318530717958647692f
#define INV_2PI_F 0.15915494309189533577f

typedef __attribute__((ext_vector_type(8))) short bf16x8;
typedef __attribute__((ext_vector_type(4))) float f32x4;
typedef unsigned long long u64;

__device__ __forceinline__ float b2f_u(unsigned short s) {
    union { unsigned u; float f; } x; x.u = ((unsigned)s) << 16; return x.f;
}
__device__ __forceinline__ unsigned short f2b(float f) {
    union { float f; unsigned u; } v; v.f = f;
    unsigned r = v.u + 0x7FFFu + ((v.u >> 16) & 1u);   // RTNE
    return (unsigned short)(r >> 16);
}
template<bool F32>
__device__ __forceinline__ uint4 load_pack8(const void* p, size_t off) {
    if (!F32) return *(const uint4*)((const unsigned short*)p + off);
    const float* fp = (const float*)p + off;
    float4 a = *(const float4*)fp;
    float4 b = *(const float4*)(fp + 4);
    uint4 r;
    r.x = (unsigned)f2b(a.x) | ((unsigned)f2b(a.y) << 16);
    r.y = (unsigned)f2b(a.z) | ((unsigned)f2b(a.w) << 16);
    r.z = (unsigned)f2b(b.x) | ((unsigned)f2b(b.y) << 16);
    r.w = (unsigned)f2b(b.z) | ((unsigned)f2b(b.w) << 16);
    return r;
}
__device__ __forceinline__ void load8_rt(int f32, const void* p, int i, float* f) {
    if (f32) {
        const float* fp = (const float*)p + i;
        float4 a = *(const float4*)fp;
        float4 b = *(const float4*)(fp + 4);
        f[0]=a.x; f[1]=a.y; f[2]=a.z; f[3]=a.w;
        f[4]=b.x; f[5]=b.y; f[6]=b.z; f[7]=b.w;
    } else {
        uint4 u = *(const uint4*)((const unsigned short*)p + i);
        f[0] = b2f_u(u.x & 0xFFFFu); f[1] = b2f_u(u.x >> 16);
        f[2] = b2f_u(u.y & 0xFFFFu); f[3] = b2f_u(u.y >> 16);
        f[4] = b2f_u(u.z & 0xFFFFu); f[5] = b2f_u(u.z >> 16);
        f[6] = b2f_u(u.w & 0xFFFFu); f[7] = b2f_u(u.w >> 16);
    }
}
__device__ __forceinline__ float read_cs_bf16(const void* p) {
    float vb = b2f_u(*(const unsigned short*)p);
    bool ok = isfinite(vb) && fabsf(vb) > 1e-30f && fabsf(vb) < 1e30f;
    if (ok) return vb;
    return *(const float*)p;
}
__device__ __forceinline__ int detect_inline(const unsigned short* x) {
    int l = threadIdx.x & 63;
    float a0 = fabsf(b2f_u(x[2 * l]));
    float a1 = fabsf(b2f_u(x[2 * (l + 64)]));
    unsigned long long b0 = __ballot(!(a0 >= 1e-10f && a0 <= 100.0f));
    unsigned long long b1 = __ballot(!(a1 >= 1e-10f && a1 <= 100.0f));
    return (__popcll(b0) + __popcll(b1)) > 16;
}
// LLC-coherent 8B access (sc0 sc1; no cache-maintenance instructions)
__device__ __forceinline__ void st8_llc(void* p, u64 v) {
    __hip_atomic_store((u64*)p, v, __ATOMIC_RELAXED, __HIP_MEMORY_SCOPE_AGENT);
}
__device__ __forceinline__ u64 ld8_llc(const void* p) {
    return __hip_atomic_load((const u64*)p, __ATOMIC_RELAXED, __HIP_MEMORY_SCOPE_AGENT);
}
__device__ __forceinline__ void wait_ctr(unsigned int* c, unsigned target) {
    unsigned spins = 0;
    while (__hip_atomic_load(c, __ATOMIC_RELAXED, __HIP_MEMORY_SCOPE_AGENT) < target) {
        __builtin_amdgcn_s_sleep(32);                  // ~2048 cyc
        if (++spins > (1u << 17)) break;               // bounded: cannot hang
    }
}

// ---------------------------------------------------------------------------
// K1: MFMA projection GEMM. Grid 288 = 32 i x 9 f. ftile 0-3 -> Qb(x0.125),
// 4-7 -> Kb, 8 -> PH0(+bp) + SC0. Block 0 zeroes the 40 barrier counters.
// ---------------------------------------------------------------------------
template<bool F32>
__device__ void projm_impl(
    const void* __restrict__ x, const void* __restrict__ Wq,
    const void* __restrict__ Wk, const void* __restrict__ Wp,
    const void* __restrict__ bp,
    unsigned short* __restrict__ Qb, unsigned short* __restrict__ Kb,
    float* __restrict__ PH, unsigned short* __restrict__ SC)
{
    __shared__ uint4 Xsh[64 * 32];   // 32 KB
    __shared__ uint4 Wsh[64 * 32];   // 32 KB
    const int tid = threadIdx.x;
    const int ftile = blockIdx.x % 9, itile = blockIdx.x / 9;
    const int i0 = itile * 64, f0 = ftile * 64;
    const int wave = tid >> 6, lane = tid & 63;
    const int n = lane & 15, quad = lane >> 4;

    #pragma unroll
    for (int g = 0; g < 8; g++) {
        int fidx = g * 256 + tid;
        int row = fidx >> 5, q = fidx & 31;
        int sw = (q & 24) | ((q ^ row) & 7);
        Xsh[row * 32 + sw] = load_pack8<F32>(x, (size_t)(i0 + row) * 256 + q * 8);
        int wr = f0 + row;
        uint4 wv = make_uint4(0, 0, 0, 0);
        if (wr < 256)      wv = load_pack8<F32>(Wq, (size_t)wr * 256 + q * 8);
        else if (wr < 512) wv = load_pack8<F32>(Wk, (size_t)(wr - 256) * 256 + q * 8);
        else if (wr < 544) wv = load_pack8<F32>(Wp, (size_t)(wr - 512) * 256 + q * 8);
        Wsh[row * 32 + sw] = wv;
    }
    __syncthreads();

    f32x4 acc[4];
    #pragma unroll
    for (int s = 0; s < 4; s++) acc[s] = (f32x4){0.f, 0.f, 0.f, 0.f};
    const int xrow = wave * 16 + n;
    #pragma unroll
    for (int s = 0; s < 8; s++) {
        int qc = s * 4 + quad;
        bf16x8 b = ((const bf16x8*)Xsh)[xrow * 32 + ((qc & 24) | ((qc ^ xrow) & 7))];
        #pragma unroll
        for (int sub = 0; sub < 4; sub++) {
            int wr = sub * 16 + n;
            bf16x8 a = ((const bf16x8*)Wsh)[wr * 32 + ((qc & 24) | ((qc ^ wr) & 7))];
            acc[sub] = __builtin_amdgcn_mfma_f32_16x16x32_bf16(a, b, acc[sub], 0, 0, 0);
        }
    }

    const int ig = i0 + wave * 16 + n;
    const int bb = ig >> 10, nr = ig & 1023;
    if (ftile < 4) {
        #pragma unroll
        for (int sub = 0; sub < 4; sub++) {
            int dd = sub * 16 + quad * 4;
            ushort4 v = make_ushort4(f2b(acc[sub][0] * 0.125f), f2b(acc[sub][1] * 0.125f),
                                     f2b(acc[sub][2] * 0.125f), f2b(acc[sub][3] * 0.125f));
            *(ushort4*)(Qb + ((size_t)((bb * NH + ftile) * NB + nr)) * 64 + dd) = v;
        }
    } else if (ftile < 8) {
        int h = ftile - 4;
        #pragma unroll
        for (int sub = 0; sub < 4; sub++) {
            int dd = sub * 16 + quad * 4;
            ushort4 v = make_ushort4(f2b(acc[sub][0]), f2b(acc[sub][1]),
                                     f2b(acc[sub][2]), f2b(acc[sub][3]));
            *(ushort4*)(Kb + ((size_t)((bb * NH + h) * NB + nr)) * 64 + dd) = v;
        }
    } else {
        #pragma unroll
        for (int sub = 0; sub < 2; sub++) {
            #pragma unroll
            for (int r = 0; r < 4; r++) {
                int fp = sub * 16 + quad * 4 + r;       // 0..31
                int h2 = fp >> 3, o = fp & 7;
                float bpv = F32 ? ((const float*)bp)[fp]
                                : b2f_u(((const unsigned short*)bp)[fp]);
                float v = acc[sub][r] + bpv;
                int bh = bb * NH + h2;
                PH[(size_t)bh * 8192 + o * 1024 + nr] = v;
                float sv, cv;
                __sincosf(v, &sv, &cv);
                SC[(size_t)(bh * 16 + o) * 1024 + nr]     = f2b(sv);
                SC[(size_t)(bh * 16 + 8 + o) * 1024 + nr] = f2b(cv);
            }
        }
    }
}

__global__ __launch_bounds__(256) void k_projm(
    const unsigned short* x, const void* Wq, const void* Wk, const void* Wp,
    const void* bp, unsigned short* Qb, unsigned short* Kb, float* PH,
    unsigned short* SC, unsigned int* ctr)
{
    if (blockIdx.x == 0) {
        #pragma unroll
        for (int i = 0; i < 5; i++) ctr[threadIdx.x + 256 * i] = 0u;
    }
    if (detect_inline(x)) projm_impl<true >(x, Wq, Wk, Wp, bp, Qb, Kb, PH, SC);
    else                  projm_impl<false>(x, Wq, Wk, Wp, bp, Qb, Kb, PH, SC);
}

// ---------------------------------------------------------------------------
// K2: mega kernel, fence-free. Grid 512 = 8 bh x 64 chunks of 16 rows.
// Barrier counter for (step k, bh): ctr[(k*8+bh)*32] — own 128B line.
// ---------------------------------------------------------------------------
__global__ __launch_bounds__(256) void k_mega3(
    const unsigned short* __restrict__ xraw,
    const unsigned short* __restrict__ Qb, const unsigned short* __restrict__ Kb,
    const float* __restrict__ PH0,
    unsigned short* __restrict__ SC0, unsigned short* __restrict__ SCA,
    const void* __restrict__ omega, const void* __restrict__ csp,
    const void* __restrict__ Wo, const void* __restrict__ bo,
    void* __restrict__ out, unsigned int* __restrict__ ctr)
{
    __shared__ uint4 Ush[16 * 128];   // 32 KB block-private U tile
    __shared__ f32x4 red[4][64];      // 4 KB
    __shared__ float redS[4][16];
    __shared__ float Rsh[16];
    __shared__ float sig[4][32];

    const int tid = threadIdx.x;
    const int bid = blockIdx.x;
    const int bh  = bid >> 6;
    const int i0  = (bid & 63) * 16;
    const int wave = tid >> 6, lane = tid & 63;
    const int n = lane & 15, quad = lane >> 4;
    const int f32 = detect_inline(xraw);

    // ---- phase A: scores + exp -> Ush (LDS only), rowsum -> Rsh ----
    const unsigned short* qrow = Qb + ((size_t)(bh * NB) + i0 + n) * 64;
    bf16x8 bq0 = *(const bf16x8*)(qrow + quad * 8);
    bf16x8 bq1 = *(const bf16x8*)(qrow + 32 + quad * 8);
    float s = 0.f;
    const unsigned short* kbase = Kb + ((size_t)(bh * NB) + n) * 64;
    #pragma unroll
    for (int t = 0; t < 16; t++) {
        int jt = wave * 16 + t;                       // j-tile 0..63
        const unsigned short* arow = kbase + (size_t)jt * 16 * 64;
        bf16x8 a0 = *(const bf16x8*)(arow + quad * 8);
        bf16x8 a1 = *(const bf16x8*)(arow + 32 + quad * 8);
        f32x4 acc = {0.f, 0.f, 0.f, 0.f};
        acc = __builtin_amdgcn_mfma_f32_16x16x32_bf16(a0, bq0, acc, 0, 0, 0);
        acc = __builtin_amdgcn_mfma_f32_16x16x32_bf16(a1, bq1, acc, 0, 0, 0);
        float u0 = __expf(acc[0]);
        float u1 = __expf(acc[1]);
        float u2 = __expf(acc[2]);
        float u3 = __expf(acc[3]);
        s += (u0 + u1) + (u2 + u3);
        ushort4 uv = make_ushort4(f2b(u0), f2b(u1), f2b(u2), f2b(u3));
        int cw = 2 * jt + (quad >> 1);
        ((ushort4*)Ush)[(n * 128 + (cw ^ (n & 7))) * 2 + (quad & 1)] = uv;
    }
    s += __shfl_xor(s, 16);
    s += __shfl_xor(s, 32);
    if (lane < 16) redS[wave][lane] = s;
    __syncthreads();
    if (tid < 16)
        Rsh[tid] = 1.0f / (redS[0][tid] + redS[1][tid] + redS[2][tid] + redS[3][tid]);

    // ---- wave-0 persistent oscillator state ----
    float P[4];
    float cs_ = 0.f, om_ = 0.f;
    if (wave == 0 && n < 8) {
        const int o = n, h = bh & 3;
        cs_ = f32 ? *(const float*)csp : read_cs_bf16(csp);
        om_ = f32 ? ((const float*)omega)[h * NO + o]
                  : b2f_u(((const unsigned short*)omega)[h * NO + o]);
        float4 pv = *(const float4*)(PH0 + (size_t)bh * 8192 + o * 1024 + i0 + quad * 4);
        P[0] = pv.x; P[1] = pv.y; P[2] = pv.z; P[3] = pv.w;
    }

    unsigned short* scin  = SC0;
    unsigned short* scout = SCA;

    // ---- 5 steps; per-bh fence-free barrier between ----
    #pragma unroll 1
    for (int k = 0; k < 5; k++) {
        const unsigned short* scrow = scin + (size_t)(bh * 16 + n) * 1024;
        f32x4 acc = {0.f, 0.f, 0.f, 0.f};
        #pragma unroll
        for (int t = 0; t < 8; t++) {
            int it = wave * 8 + t;
            bf16x8 a = ((const bf16x8*)Ush)[n * 128 + ((it * 4 + quad) ^ (n & 7))];
            union { u64 q[2]; bf16x8 v; } bb;
            bb.q[0] = ld8_llc(scrow + it * 32 + quad * 8);
            bb.q[1] = ld8_llc(scrow + it * 32 + quad * 8 + 4);
            acc = __builtin_amdgcn_mfma_f32_16x16x32_bf16(bb.v, bb.v, acc, 0, 0, 0);
            acc[0] = acc[0];   // placeholder removed below
        }
        // NOTE: loop above rewritten correctly just after (kept single version)
        // -- the real loop:
        acc = (f32x4){0.f, 0.f, 0.f, 0.f};
        #pragma unroll
        for (int t = 0; t < 8; t++) {
            int it = wave * 8 + t;
            bf16x8 a = ((const bf16x8*)Ush)[n * 128 + ((it * 4 + quad) ^ (n & 7))];
            union { u64 q[2]; bf16x8 v; } bb;
            const unsigned short* bp8 = scrow + it * 32 + quad * 8;
            bb.q[0] = ld8_llc(bp8);
            bb.q[1] = ld8_llc(bp8 + 4);
            acc = __builtin_amdgcn_mfma_f32_16x16x32_bf16(a, bb.v, acc, 0, 0, 0);
        }
        red[wave][lane] = acc;
        __syncthreads();

        if (wave == 0) {
            f32x4 a0 = red[0][lane], a1 = red[1][lane];
            f32x4 a2 = red[2][lane], a3 = red[3][lane];
            #pragma unroll
            for (int v = 0; v < 4; v++) acc[v] = (a0[v] + a1[v]) + (a2[v] + a3[v]);
            float C0 = __shfl_xor(acc[0], 8);
            float C1 = __shfl_xor(acc[1], 8);
            float C2 = __shfl_xor(acc[2], 8);
            float C3 = __shfl_xor(acc[3], 8);
            if (n < 8) {
                const int o = n;
                float S[4] = {acc[0], acc[1], acc[2], acc[3]};
                float C[4] = {C0, C1, C2, C3};
                float Rr[4] = {Rsh[quad * 4], Rsh[quad * 4 + 1],
                               Rsh[quad * 4 + 2], Rsh[quad * 4 + 3]};
                unsigned short sb[4], cb[4];
                #pragma unroll
                for (int r = 0; r < 4; r++) {
                    float si, ci;
                    __sincosf(P[r], &si, &ci);
                    float coup = (ci * S[r] - si * C[r]) * Rr[r];
                    float v = P[r] + 0.1f * (om_ + cs_ * coup);
                    float t2 = v + PI_F;
                    t2 -= floorf(t2 * INV_2PI_F) * TWO_PI_F;   // jnp.remainder
                    P[r] = t2 - PI_F;
                    float sn, cn;
                    __sincosf(P[r], &sn, &cn);
                    sb[r] = f2b(sn); cb[r] = f2b(cn);
                }
                u64 sv = (u64)sb[0] | ((u64)sb[1] << 16) | ((u64)sb[2] << 32) | ((u64)sb[3] << 48);
                u64 cv = (u64)cb[0] | ((u64)cb[1] << 16) | ((u64)cb[2] << 32) | ((u64)cb[3] << 48);
                int i = i0 + quad * 4;
                st8_llc(scout + (size_t)(bh * 16 + o) * 1024 + i,     sv);
                st8_llc(scout + (size_t)(bh * 16 + 8 + o) * 1024 + i, cv);
            }
        }
        __syncthreads();   // vmcnt(0) drain: all SC stores visible before signal
        if (tid == 0) {
            unsigned int* c = &ctr[(k * 8 + bh) * 32];
            atomicAdd(c, 1u);                  // device-scope (m20)
            if (k < 4) wait_ctr(c, 64u);       // steps 1-4 need own bh only
        }
        if (k == 4 && tid < 4) {               // output needs 4 bh's of batch ob
            int ob = bid >> 8;
            wait_ctr(&ctr[(4 * 8 + (ob * NH + tid)) * 32], 64u);
        }
        __syncthreads();
        unsigned short* tmp = scin; scin = scout; scout = tmp;
    }

    // ---- fused output projection: bid -> (b = bid>>8, 4 n-rows) ----
    const int ob = bid >> 8, n0 = (bid & 255) * 4;
    if (tid < 32) {
        int h = tid >> 3, o = tid & 7;
        union { u64 q; unsigned short w[4]; } cw;
        cw.q = ld8_llc(scin + (size_t)((ob * NH + h) * 16 + 8 + o) * 1024 + n0);
        #pragma unroll
        for (int r = 0; r < 4; r++) sig[r][tid] = b2f_u(cw.w[r]);
    }
    __syncthreads();
    float wv[32];
    #pragma unroll
    for (int d0 = 0; d0 < 32; d0 += 8) load8_rt(f32, Wo, tid * 32 + d0, wv + d0);
    const float bov = f32 ? ((const float*)bo)[tid] : b2f_u(((const unsigned short*)bo)[tid]);
    #pragma unroll
    for (int r = 0; r < 4; r++) {
        float acc = bov;
        #pragma unroll
        for (int t = 0; t < 32; t++) acc += sig[r][t] * wv[t];
        size_t oi = ((size_t)ob * 1024 + n0 + r) * DD + tid;
        if (f32) ((float*)out)[oi] = acc;
        else     ((unsigned short*)out)[oi] = f2b(acc);
    }
}

// ---------------------------------------------------------------------------
extern "C" void kernel_launch(void* const* d_in, const int* in_sizes, int n_in,
                              void* d_out, int out_size, void* d_ws, size_t ws_size,
                              hipStream_t stream)
{
    const unsigned short* x = (const unsigned short*)d_in[0];
    const void* Wq  = d_in[1];
    const void* Wk  = d_in[2];
    const void* Wp  = d_in[3];
    const void* bp  = d_in[4];
    const void* Wo  = d_in[5];
    const void* bo  = d_in[6];
    const void* om  = d_in[7];
    const void* cs  = d_in[8];

    char* w = (char*)d_ws;
    unsigned short* Qb  = (unsigned short*)w;
    unsigned short* Kb  = (unsigned short*)(w + (1u << 20));
    float*          PH0 = (float*)(w + (2u << 20));
    unsigned short* SC0 = (unsigned short*)(w + (2u << 20) + (256u << 10));
    unsigned short* SCA = (unsigned short*)(w + (2u << 20) + (512u << 10));
    unsigned int*   ctr = (unsigned int*)(w + (3u << 20));

    k_projm<<<288, 256, 0, stream>>>(x, Wq, Wk, Wp, bp, Qb, Kb, PH0, SC0, ctr);
    k_mega3<<<512, 256, 0, stream>>>(x, Qb, Kb, PH0, SC0, SCA, om, cs,
                                     Wo, bo, d_out, ctr);
}

// Round 12
// 121.157 us; speedup vs baseline: 3.6034x; 1.3972x over previous
//
#include <hip/hip_runtime.h>
#include <hip/hip_bf16.h>
#include <math.h>

// AKOrN layer: B=2, N=1024, D=256, H=4 (dk=64), O=8, DT=0.1, STEPS=5
// TWO plain launches.
// R10 lesson: __threadfence() = full L2 wb/inv -> ~70us/barrier. R11 lesson:
// per-8B coherent ATOMIC loads are slow + I shipped a dead duplicate load
// loop. R12: writes stay agent-scope (write-through to LLC, proven correct);
// READS become normal b128 loads against 6 write-once SC buffers -- a reader
// has never cached those addresses, so stale lines are impossible and no
// coherent load/fence is needed.
//
//   k_projm : dtype-detect + bf16 cvt; MFMA GEMM -> Qb(x0.125), Kb,
//             PH0 fp32 [bh][o][n], SCb[0] bf16 sin/cos; zeroes counters.
//   k_mega4 : scores+exp -> U in LDS (block-private), rowsum -> Rsh;
//             5 Kuramoto steps (phases in wave-0 regs; SCb[k] -> SCb[k+1];
//             per-bh bounded-spin barrier); fused output projection.
//
// Workspace: Qb @0 (1M) | Kb @1M (1M) | PH0 @2M (256K) | SCB @2M+256K (6x256K)
//            ctr @4M (5KB)

#define NB 1024
#define NH 4
#define DD 256
#define NO 8
#define SCSZ 131072               // ushorts per SC buffer (256 KB)
#define PI_F      3.14159265358979323846f
#define TWO_PI_F  6.28318530717958647692f
#define INV_2PI_F 0.15915494309189533577f

typedef __attribute__((ext_vector_type(8))) short bf16x8;
typedef __attribute__((ext_vector_type(4))) float f32x4;
typedef unsigned long long u64;

__device__ __forceinline__ float b2f_u(unsigned short s) {
    union { unsigned u; float f; } x; x.u = ((unsigned)s) << 16; return x.f;
}
__device__ __forceinline__ unsigned short f2b(float f) {
    union { float f; unsigned u; } v; v.f = f;
    unsigned r = v.u + 0x7FFFu + ((v.u >> 16) & 1u);   // RTNE
    return (unsigned short)(r >> 16);
}
template<bool F32>
__device__ __forceinline__ uint4 load_pack8(const void* p, size_t off) {
    if (!F32) return *(const uint4*)((const unsigned short*)p + off);
    const float* fp = (const float*)p + off;
    float4 a = *(const float4*)fp;
    float4 b = *(const float4*)(fp + 4);
    uint4 r;
    r.x = (unsigned)f2b(a.x) | ((unsigned)f2b(a.y) << 16);
    r.y = (unsigned)f2b(a.z) | ((unsigned)f2b(a.w) << 16);
    r.z = (unsigned)f2b(b.x) | ((unsigned)f2b(b.y) << 16);
    r.w = (unsigned)f2b(b.z) | ((unsigned)f2b(b.w) << 16);
    return r;
}
__device__ __forceinline__ void load8_rt(int f32, const void* p, int i, float* f) {
    if (f32) {
        const float* fp = (const float*)p + i;
        float4 a = *(const float4*)fp;
        float4 b = *(const float4*)(fp + 4);
        f[0]=a.x; f[1]=a.y; f[2]=a.z; f[3]=a.w;
        f[4]=b.x; f[5]=b.y; f[6]=b.z; f[7]=b.w;
    } else {
        uint4 u = *(const uint4*)((const unsigned short*)p + i);
        f[0] = b2f_u(u.x & 0xFFFFu); f[1] = b2f_u(u.x >> 16);
        f[2] = b2f_u(u.y & 0xFFFFu); f[3] = b2f_u(u.y >> 16);
        f[4] = b2f_u(u.z & 0xFFFFu); f[5] = b2f_u(u.z >> 16);
        f[6] = b2f_u(u.w & 0xFFFFu); f[7] = b2f_u(u.w >> 16);
    }
}
__device__ __forceinline__ float read_cs_bf16(const void* p) {
    float vb = b2f_u(*(const unsigned short*)p);
    bool ok = isfinite(vb) && fabsf(vb) > 1e-30f && fabsf(vb) < 1e30f;
    if (ok) return vb;
    return *(const float*)p;
}
__device__ __forceinline__ int detect_inline(const unsigned short* x) {
    int l = threadIdx.x & 63;
    float a0 = fabsf(b2f_u(x[2 * l]));
    float a1 = fabsf(b2f_u(x[2 * (l + 64)]));
    unsigned long long b0 = __ballot(!(a0 >= 1e-10f && a0 <= 100.0f));
    unsigned long long b1 = __ballot(!(a1 >= 1e-10f && a1 <= 100.0f));
    return (__popcll(b0) + __popcll(b1)) > 16;
}
// agent-scope write-through 8B store (reaches LLC; proven R10/R11)
__device__ __forceinline__ void st8_llc(void* p, u64 v) {
    __hip_atomic_store((u64*)p, v, __ATOMIC_RELAXED, __HIP_MEMORY_SCOPE_AGENT);
}
__device__ __forceinline__ void wait_ctr(unsigned int* c, unsigned target) {
    unsigned spins = 0;
    while (__hip_atomic_load(c, __ATOMIC_RELAXED, __HIP_MEMORY_SCOPE_AGENT) < target) {
        __builtin_amdgcn_s_sleep(8);                   // ~512 cyc
        if (++spins > (1u << 18)) break;               // bounded: cannot hang
    }
}

// ---------------------------------------------------------------------------
// K1: MFMA projection GEMM. Grid 288 = 32 i x 9 f. ftile 0-3 -> Qb(x0.125),
// 4-7 -> Kb, 8 -> PH0(+bp) + SCb[0]. Block 0 zeroes barrier counters.
// ---------------------------------------------------------------------------
template<bool F32>
__device__ void projm_impl(
    const void* __restrict__ x, const void* __restrict__ Wq,
    const void* __restrict__ Wk, const void* __restrict__ Wp,
    const void* __restrict__ bp,
    unsigned short* __restrict__ Qb, unsigned short* __restrict__ Kb,
    float* __restrict__ PH, unsigned short* __restrict__ SC)
{
    __shared__ uint4 Xsh[64 * 32];   // 32 KB
    __shared__ uint4 Wsh[64 * 32];   // 32 KB
    const int tid = threadIdx.x;
    const int ftile = blockIdx.x % 9, itile = blockIdx.x / 9;
    const int i0 = itile * 64, f0 = ftile * 64;
    const int wave = tid >> 6, lane = tid & 63;
    const int n = lane & 15, quad = lane >> 4;

    #pragma unroll
    for (int g = 0; g < 8; g++) {
        int fidx = g * 256 + tid;
        int row = fidx >> 5, q = fidx & 31;
        int sw = (q & 24) | ((q ^ row) & 7);
        Xsh[row * 32 + sw] = load_pack8<F32>(x, (size_t)(i0 + row) * 256 + q * 8);
        int wr = f0 + row;
        uint4 wv = make_uint4(0, 0, 0, 0);
        if (wr < 256)      wv = load_pack8<F32>(Wq, (size_t)wr * 256 + q * 8);
        else if (wr < 512) wv = load_pack8<F32>(Wk, (size_t)(wr - 256) * 256 + q * 8);
        else if (wr < 544) wv = load_pack8<F32>(Wp, (size_t)(wr - 512) * 256 + q * 8);
        Wsh[row * 32 + sw] = wv;
    }
    __syncthreads();

    f32x4 acc[4];
    #pragma unroll
    for (int s = 0; s < 4; s++) acc[s] = (f32x4){0.f, 0.f, 0.f, 0.f};
    const int xrow = wave * 16 + n;
    #pragma unroll
    for (int s = 0; s < 8; s++) {
        int qc = s * 4 + quad;
        bf16x8 b = ((const bf16x8*)Xsh)[xrow * 32 + ((qc & 24) | ((qc ^ xrow) & 7))];
        #pragma unroll
        for (int sub = 0; sub < 4; sub++) {
            int wr = sub * 16 + n;
            bf16x8 a = ((const bf16x8*)Wsh)[wr * 32 + ((qc & 24) | ((qc ^ wr) & 7))];
            acc[sub] = __builtin_amdgcn_mfma_f32_16x16x32_bf16(a, b, acc[sub], 0, 0, 0);
        }
    }

    const int ig = i0 + wave * 16 + n;
    const int bb = ig >> 10, nr = ig & 1023;
    if (ftile < 4) {
        #pragma unroll
        for (int sub = 0; sub < 4; sub++) {
            int dd = sub * 16 + quad * 4;
            ushort4 v = make_ushort4(f2b(acc[sub][0] * 0.125f), f2b(acc[sub][1] * 0.125f),
                                     f2b(acc[sub][2] * 0.125f), f2b(acc[sub][3] * 0.125f));
            *(ushort4*)(Qb + ((size_t)((bb * NH + ftile) * NB + nr)) * 64 + dd) = v;
        }
    } else if (ftile < 8) {
        int h = ftile - 4;
        #pragma unroll
        for (int sub = 0; sub < 4; sub++) {
            int dd = sub * 16 + quad * 4;
            ushort4 v = make_ushort4(f2b(acc[sub][0]), f2b(acc[sub][1]),
                                     f2b(acc[sub][2]), f2b(acc[sub][3]));
            *(ushort4*)(Kb + ((size_t)((bb * NH + h) * NB + nr)) * 64 + dd) = v;
        }
    } else {
        #pragma unroll
        for (int sub = 0; sub < 2; sub++) {
            #pragma unroll
            for (int r = 0; r < 4; r++) {
                int fp = sub * 16 + quad * 4 + r;       // 0..31
                int h2 = fp >> 3, o = fp & 7;
                float bpv = F32 ? ((const float*)bp)[fp]
                                : b2f_u(((const unsigned short*)bp)[fp]);
                float v = acc[sub][r] + bpv;
                int bh = bb * NH + h2;
                PH[(size_t)bh * 8192 + o * 1024 + nr] = v;
                float sv, cv;
                __sincosf(v, &sv, &cv);
                SC[(size_t)(bh * 16 + o) * 1024 + nr]     = f2b(sv);
                SC[(size_t)(bh * 16 + 8 + o) * 1024 + nr] = f2b(cv);
            }
        }
    }
}

__global__ __launch_bounds__(256) void k_projm(
    const unsigned short* x, const void* Wq, const void* Wk, const void* Wp,
    const void* bp, unsigned short* Qb, unsigned short* Kb, float* PH,
    unsigned short* SC, unsigned int* ctr)
{
    if (blockIdx.x == 0) {
        #pragma unroll
        for (int i = 0; i < 5; i++) ctr[threadIdx.x + 256 * i] = 0u;
    }
    if (detect_inline(x)) projm_impl<true >(x, Wq, Wk, Wp, bp, Qb, Kb, PH, SC);
    else                  projm_impl<false>(x, Wq, Wk, Wp, bp, Qb, Kb, PH, SC);
}

// ---------------------------------------------------------------------------
// K2: mega kernel. Grid 512 = 8 bh x 64 chunks of 16 rows; ~37 KB LDS ->
// 2 blocks/CU -> all 512 co-resident. SCb[k] is write-once/read-once, so
// step reads are NORMAL b128 loads (stale lines impossible).
// Barrier counter for (step k, bh): ctr[(k*8+bh)*32] — own 128B line.
// ---------------------------------------------------------------------------
__global__ __launch_bounds__(256) void k_mega4(
    const unsigned short* __restrict__ xraw,
    const unsigned short* __restrict__ Qb, const unsigned short* __restrict__ Kb,
    const float* __restrict__ PH0,
    unsigned short* __restrict__ SCB,
    const void* __restrict__ omega, const void* __restrict__ csp,
    const void* __restrict__ Wo, const void* __restrict__ bo,
    void* __restrict__ out, unsigned int* __restrict__ ctr)
{
    __shared__ uint4 Ush[16 * 128];   // 32 KB block-private U tile
    __shared__ f32x4 red[4][64];      // 4 KB
    __shared__ float redS[4][16];
    __shared__ float Rsh[16];
    __shared__ float sig[4][32];

    const int tid = threadIdx.x;
    const int bid = blockIdx.x;
    const int bh  = bid >> 6;
    const int i0  = (bid & 63) * 16;
    const int wave = tid >> 6, lane = tid & 63;
    const int n = lane & 15, quad = lane >> 4;
    const int f32 = detect_inline(xraw);

    // ---- phase A: scores + exp -> Ush (LDS only), rowsum -> Rsh ----
    const unsigned short* qrow = Qb + ((size_t)(bh * NB) + i0 + n) * 64;
    bf16x8 bq0 = *(const bf16x8*)(qrow + quad * 8);
    bf16x8 bq1 = *(const bf16x8*)(qrow + 32 + quad * 8);
    float s = 0.f;
    const unsigned short* kbase = Kb + ((size_t)(bh * NB) + n) * 64;
    #pragma unroll
    for (int t = 0; t < 16; t++) {
        int jt = wave * 16 + t;                       // j-tile 0..63
        const unsigned short* arow = kbase + (size_t)jt * 16 * 64;
        bf16x8 a0 = *(const bf16x8*)(arow + quad * 8);
        bf16x8 a1 = *(const bf16x8*)(arow + 32 + quad * 8);
        f32x4 acc = {0.f, 0.f, 0.f, 0.f};
        acc = __builtin_amdgcn_mfma_f32_16x16x32_bf16(a0, bq0, acc, 0, 0, 0);
        acc = __builtin_amdgcn_mfma_f32_16x16x32_bf16(a1, bq1, acc, 0, 0, 0);
        float u0 = __expf(acc[0]);
        float u1 = __expf(acc[1]);
        float u2 = __expf(acc[2]);
        float u3 = __expf(acc[3]);
        s += (u0 + u1) + (u2 + u3);
        ushort4 uv = make_ushort4(f2b(u0), f2b(u1), f2b(u2), f2b(u3));
        int cw = 2 * jt + (quad >> 1);
        ((ushort4*)Ush)[(n * 128 + (cw ^ (n & 7))) * 2 + (quad & 1)] = uv;
    }
    s += __shfl_xor(s, 16);
    s += __shfl_xor(s, 32);
    if (lane < 16) redS[wave][lane] = s;
    __syncthreads();
    if (tid < 16)
        Rsh[tid] = 1.0f / (redS[0][tid] + redS[1][tid] + redS[2][tid] + redS[3][tid]);

    // ---- wave-0 persistent oscillator state ----
    float P[4];
    float cs_ = 0.f, om_ = 0.f;
    if (wave == 0 && n < 8) {
        const int o = n, h = bh & 3;
        cs_ = f32 ? *(const float*)csp : read_cs_bf16(csp);
        om_ = f32 ? ((const float*)omega)[h * NO + o]
                  : b2f_u(((const unsigned short*)omega)[h * NO + o]);
        float4 pv = *(const float4*)(PH0 + (size_t)bh * 8192 + o * 1024 + i0 + quad * 4);
        P[0] = pv.x; P[1] = pv.y; P[2] = pv.z; P[3] = pv.w;
    }

    // ---- 5 steps; SCb[k] -> SCb[k+1]; per-bh fence-free barrier ----
    #pragma unroll 1
    for (int k = 0; k < 5; k++) {
        const unsigned short* scrow = SCB + (size_t)k * SCSZ + (size_t)(bh * 16 + n) * 1024;
        unsigned short* scout       = SCB + (size_t)(k + 1) * SCSZ;
        f32x4 acc = {0.f, 0.f, 0.f, 0.f};
        #pragma unroll
        for (int t = 0; t < 8; t++) {
            int it = wave * 8 + t;
            bf16x8 a = ((const bf16x8*)Ush)[n * 128 + ((it * 4 + quad) ^ (n & 7))];
            bf16x8 b = *(const bf16x8*)(scrow + it * 32 + quad * 8);  // normal b128
            acc = __builtin_amdgcn_mfma_f32_16x16x32_bf16(a, b, acc, 0, 0, 0);
        }
        red[wave][lane] = acc;
        __syncthreads();

        if (wave == 0) {
            f32x4 a0 = red[0][lane], a1 = red[1][lane];
            f32x4 a2 = red[2][lane], a3 = red[3][lane];
            #pragma unroll
            for (int v = 0; v < 4; v++) acc[v] = (a0[v] + a1[v]) + (a2[v] + a3[v]);
            float C0 = __shfl_xor(acc[0], 8);
            float C1 = __shfl_xor(acc[1], 8);
            float C2 = __shfl_xor(acc[2], 8);
            float C3 = __shfl_xor(acc[3], 8);
            if (n < 8) {
                const int o = n;
                float S[4] = {acc[0], acc[1], acc[2], acc[3]};
                float C[4] = {C0, C1, C2, C3};
                float Rr[4] = {Rsh[quad * 4], Rsh[quad * 4 + 1],
                               Rsh[quad * 4 + 2], Rsh[quad * 4 + 3]};
                unsigned short sb[4], cb[4];
                #pragma unroll
                for (int r = 0; r < 4; r++) {
                    float si, ci;
                    __sincosf(P[r], &si, &ci);
                    float coup = (ci * S[r] - si * C[r]) * Rr[r];
                    float v = P[r] + 0.1f * (om_ + cs_ * coup);
                    float t2 = v + PI_F;
                    t2 -= floorf(t2 * INV_2PI_F) * TWO_PI_F;   // jnp.remainder
                    P[r] = t2 - PI_F;
                    float sn, cn;
                    __sincosf(P[r], &sn, &cn);
                    sb[r] = f2b(sn); cb[r] = f2b(cn);
                }
                u64 sv = (u64)sb[0] | ((u64)sb[1] << 16) | ((u64)sb[2] << 32) | ((u64)sb[3] << 48);
                u64 cv = (u64)cb[0] | ((u64)cb[1] << 16) | ((u64)cb[2] << 32) | ((u64)cb[3] << 48);
                int i = i0 + quad * 4;
                st8_llc(scout + (size_t)(bh * 16 + o) * 1024 + i,     sv);
                st8_llc(scout + (size_t)(bh * 16 + 8 + o) * 1024 + i, cv);
            }
        }
        __syncthreads();   // vmcnt(0) drain: SC stores at LLC before signal
        if (tid == 0) {
            unsigned int* c = &ctr[(k * 8 + bh) * 32];
            atomicAdd(c, 1u);                  // device-scope
            if (k < 4) wait_ctr(c, 64u);       // steps 1-4: own bh only
        }
        if (k == 4 && tid < 4) {               // output needs 4 bh's of batch ob
            int ob = bid >> 8;
            wait_ctr(&ctr[(4 * 8 + (ob * NH + tid)) * 32], 64u);
        }
        __syncthreads();
    }

    // ---- fused output projection: bid -> (b = bid>>8, 4 n-rows) ----
    const unsigned short* scfin = SCB + (size_t)5 * SCSZ;
    const int ob = bid >> 8, n0 = (bid & 255) * 4;
    if (tid < 32) {
        int h = tid >> 3, o = tid & 7;
        // normal load: this block never read SCb[5] before -> cannot be stale
        u64 q = *(const u64*)(scfin + (size_t)((ob * NH + h) * 16 + 8 + o) * 1024 + n0);
        #pragma unroll
        for (int r = 0; r < 4; r++)
            sig[r][tid] = b2f_u((unsigned short)(q >> (16 * r)));
    }
    __syncthreads();
    float wv[32];
    #pragma unroll
    for (int d0 = 0; d0 < 32; d0 += 8) load8_rt(f32, Wo, tid * 32 + d0, wv + d0);
    const float bov = f32 ? ((const float*)bo)[tid] : b2f_u(((const unsigned short*)bo)[tid]);
    #pragma unroll
    for (int r = 0; r < 4; r++) {
        float acc = bov;
        #pragma unroll
        for (int t = 0; t < 32; t++) acc += sig[r][t] * wv[t];
        size_t oi = ((size_t)ob * 1024 + n0 + r) * DD + tid;
        if (f32) ((float*)out)[oi] = acc;
        else     ((unsigned short*)out)[oi] = f2b(acc);
    }
}

// ---------------------------------------------------------------------------
extern "C" void kernel_launch(void* const* d_in, const int* in_sizes, int n_in,
                              void* d_out, int out_size, void* d_ws, size_t ws_size,
                              hipStream_t stream)
{
    const unsigned short* x = (const unsigned short*)d_in[0];
    const void* Wq  = d_in[1];
    const void* Wk  = d_in[2];
    const void* Wp  = d_in[3];
    const void* bp  = d_in[4];
    const void* Wo  = d_in[5];
    const void* bo  = d_in[6];
    const void* om  = d_in[7];
    const void* cs  = d_in[8];

    char* w = (char*)d_ws;
    unsigned short* Qb  = (unsigned short*)w;
    unsigned short* Kb  = (unsigned short*)(w + (1u << 20));
    float*          PH0 = (float*)(w + (2u << 20));
    unsigned short* SCB = (unsigned short*)(w + (2u << 20) + (256u << 10));
    unsigned int*   ctr = (unsigned int*)(w + (4u << 20));

    k_projm<<<288, 256, 0, stream>>>(x, Wq, Wk, Wp, bp, Qb, Kb, PH0, SCB, ctr);
    k_mega4<<<512, 256, 0, stream>>>(x, Qb, Kb, PH0, SCB, om, cs,
                                     Wo, bo, d_out, ctr);
}